// Round 4
// baseline (1394.403 us; speedup 1.0000x reference)
//
#include <hip/hip_runtime.h>
#include <math.h>

#define B_     64
#define NPG_   4096
#define M_     8
#define DN_    512
#define DQ_    256
#define N_     (B_*NPG_)
#define KSEL_  1229          // ceil(0.3 * 4096)

typedef _Float16 f16x4  __attribute__((ext_vector_type(4)));
typedef _Float16 f16x8  __attribute__((ext_vector_type(8)));
typedef float    f32x16 __attribute__((ext_vector_type(16)));

// ---------------------------------------------------------------------------
// Kernel 0: split Wn[k][c] (fp32) into transposed fp16 hi/lo halves
// WnT_hi/lo[c][k], k contiguous. One-time, tiny (512 KB), parked in d_out
// (k_mask fully overwrites d_out later).
// ---------------------------------------------------------------------------
__global__ __launch_bounds__(256) void k_prep(const float* __restrict__ Wn,
                                              _Float16* __restrict__ th,
                                              _Float16* __restrict__ tl)
{
    const int k = blockIdx.x;      // 0..511
    const int c = threadIdx.x;     // 0..255
    const float w = Wn[k * DQ_ + c];
    const _Float16 h = (_Float16)w;
    th[c * DN_ + k] = h;
    tl[c * DN_ + k] = (_Float16)(w - (float)h);
}

// ---------------------------------------------------------------------------
// Kernel 1: scores[n][m] = sum_c gelu(x[n]·Wn[:,c] + bn[c]) * u[m][b(n)][c]
// fp16x2-split MFMA GEMM (hi*hi + hi*lo + lo*hi, fp32 acc).
// 64x64 wave tiles -> acc=64 AGPR, staging ~40 VGPR, ~156 unified regs vs the
// 256 cap (round-2's 128-row tile hit the cap -> 852 MB/dispatch scratch
// spill). Block = 64 rows x 256 cols, 4 col-waves, BK=32, reg-prefetch
// single-buffer LDS, 80B-stride rows. Epilogue partials alias the B tile.
// ---------------------------------------------------------------------------
__global__ __launch_bounds__(256, 2) void k_score(
    const float* __restrict__ x, const float* __restrict__ u,
    const float* __restrict__ bn,
    const _Float16* __restrict__ wth, const _Float16* __restrict__ wtl,
    float* __restrict__ scores)
{
    __shared__ __align__(16) _Float16 Ahi[64][40],  Alo[64][40];    //  5120 B each
    __shared__ __align__(16) _Float16 Bhi[256][40], Blo[256][40];   // 20480 B each
    __shared__ float usS[M_][DQ_];                                  //  8192 B
    __shared__ float bnsS[DQ_];                                     //  1024 B
    // epilogue partials alias the B tile (8 KB needed, 20 KB available);
    // a barrier separates last MFMA read of B from the first part write.
    float* part4f = (float*)&Bhi[0][0];                             // [4][64][8]
    // total LDS ~59 KB -> 2 blocks/CU

    const int tid = threadIdx.x;
    const int ln  = tid & 63;
    const int wc  = tid >> 6;          // 0..3 : 64-col group
    const int lr  = ln & 31;
    const int lh  = ln >> 5;
    const int row0 = blockIdx.x * 64;
    const int b    = row0 >> 12;       // graph id (64-row blocks never straddle)

    // stage instruction vectors + bias (epilogue-only; loop barriers cover)
    #pragma unroll
    for (int p = 0; p < 8; ++p) {
        const int idx = p * 256 + tid;
        usS[idx >> 8][idx & 255] = u[((idx >> 8) * B_ + b) * DQ_ + (idx & 255)];
    }
    bnsS[tid] = bn[tid];

    // ---- staging addresses ----
    const int arow  = tid >> 2;                // 0..63
    const int akoff = (tid & 3) * 8;           // 0,8,16,24
    const float*  xp  = x + (long)(row0 + arow) * DN_ + akoff;
    const float4* bhp = (const float4*)(wth + (long)tid * DN_);   // row c = tid
    const float4* blp = (const float4*)(wtl + (long)tid * DN_);

    float4 xa[2], bh[4], bl[4];
    #pragma unroll
    for (int i = 0; i < 2; ++i) xa[i] = ((const float4*)xp)[i];    // tile 0
    #pragma unroll
    for (int j = 0; j < 4; ++j) { bh[j] = bhp[j]; bl[j] = blp[j]; }

    f32x16 acc[2][2];
    #pragma unroll
    for (int mt = 0; mt < 2; ++mt)
        #pragma unroll
        for (int nt = 0; nt < 2; ++nt)
            #pragma unroll
            for (int r = 0; r < 16; ++r) acc[mt][nt][r] = 0.0f;

    for (int kt = 0; kt < DN_ / 32; ++kt) {
        __syncthreads();                       // previous tile fully consumed

        // write A (convert fp32 -> hi/lo fp16), one f16x8 per array
        {
            f16x8 h, l;
            h[0] = (_Float16)xa[0].x; l[0] = (_Float16)(xa[0].x - (float)h[0]);
            h[1] = (_Float16)xa[0].y; l[1] = (_Float16)(xa[0].y - (float)h[1]);
            h[2] = (_Float16)xa[0].z; l[2] = (_Float16)(xa[0].z - (float)h[2]);
            h[3] = (_Float16)xa[0].w; l[3] = (_Float16)(xa[0].w - (float)h[3]);
            h[4] = (_Float16)xa[1].x; l[4] = (_Float16)(xa[1].x - (float)h[4]);
            h[5] = (_Float16)xa[1].y; l[5] = (_Float16)(xa[1].y - (float)h[5]);
            h[6] = (_Float16)xa[1].z; l[6] = (_Float16)(xa[1].z - (float)h[6]);
            h[7] = (_Float16)xa[1].w; l[7] = (_Float16)(xa[1].w - (float)h[7]);
            *(f16x8*)&Ahi[arow][akoff] = h;
            *(f16x8*)&Alo[arow][akoff] = l;
        }
        // write B (already fp16 bits, straight copy)
        #pragma unroll
        for (int j = 0; j < 4; ++j) {
            *(float4*)&Bhi[tid][j * 8] = bh[j];
            *(float4*)&Blo[tid][j * 8] = bl[j];
        }
        __syncthreads();

        if (kt + 1 < DN_ / 32) {               // prefetch next tile into regs
            const float* xn = xp + (kt + 1) * 32;
            #pragma unroll
            for (int i = 0; i < 2; ++i) xa[i] = ((const float4*)xn)[i];
            #pragma unroll
            for (int j = 0; j < 4; ++j) {
                bh[j] = bhp[(kt + 1) * 4 + j];
                bl[j] = blp[(kt + 1) * 4 + j];
            }
        }

        // MFMA: 2 K-substeps x 2x2 tiles x 3 split products = 24 MFMA/wave
        #pragma unroll
        for (int s = 0; s < 2; ++s) {
            const int o = s * 16 + lh * 8;
            f16x8 afh[2], afl[2], bfh[2], bfl[2];
            #pragma unroll
            for (int mt = 0; mt < 2; ++mt) {
                afh[mt] = *(const f16x8*)&Ahi[mt * 32 + lr][o];
                afl[mt] = *(const f16x8*)&Alo[mt * 32 + lr][o];
            }
            #pragma unroll
            for (int nt = 0; nt < 2; ++nt) {
                const int c = wc * 64 + nt * 32 + lr;
                bfh[nt] = *(const f16x8*)&Bhi[c][o];
                bfl[nt] = *(const f16x8*)&Blo[c][o];
            }
            #pragma unroll
            for (int mt = 0; mt < 2; ++mt)
                #pragma unroll
                for (int nt = 0; nt < 2; ++nt) {
                    acc[mt][nt] = __builtin_amdgcn_mfma_f32_32x32x16_f16(
                        afh[mt], bfh[nt], acc[mt][nt], 0, 0, 0);
                    acc[mt][nt] = __builtin_amdgcn_mfma_f32_32x32x16_f16(
                        afh[mt], bfl[nt], acc[mt][nt], 0, 0, 0);
                    acc[mt][nt] = __builtin_amdgcn_mfma_f32_32x32x16_f16(
                        afl[mt], bfh[nt], acc[mt][nt], 0, 0, 0);
                }
        }
    }

    // ---- epilogue: bias + exact gelu, in place (register-only) ----
    #pragma unroll
    for (int mt = 0; mt < 2; ++mt)
        #pragma unroll
        for (int nt = 0; nt < 2; ++nt) {
            const float bnc = bnsS[wc * 64 + nt * 32 + lr];
            #pragma unroll
            for (int r = 0; r < 16; ++r) {
                const float z = acc[mt][nt][r] + bnc;
                acc[mt][nt][r] = 0.5f * z * (1.0f + erff(z * 0.7071067811865476f));
            }
        }

    __syncthreads();     // all waves done reading B LDS; part4f may alias it

    // dot with 8 instruction vectors; shfl-reduce over the wave's 64 cols
    #pragma unroll 1
    for (int m = 0; m < 8; ++m) {
        const float u0 = usS[m][wc * 64 +  0 + lr];
        const float u1 = usS[m][wc * 64 + 32 + lr];
        float p[2][16];
        #pragma unroll
        for (int mt = 0; mt < 2; ++mt)
            #pragma unroll
            for (int r = 0; r < 16; ++r)
                p[mt][r] = acc[mt][0][r] * u0 + acc[mt][1][r] * u1;
        #pragma unroll
        for (int mask = 1; mask < 32; mask <<= 1)
            #pragma unroll
            for (int mt = 0; mt < 2; ++mt)
                #pragma unroll
                for (int r = 0; r < 16; ++r)
                    p[mt][r] += __shfl_xor(p[mt][r], mask, 64);
        if (lr == m) {                          // lanes m and 32+m: disjoint rows
            #pragma unroll
            for (int mt = 0; mt < 2; ++mt)
                #pragma unroll
                for (int r = 0; r < 16; ++r) {
                    const int row = mt * 32 + (r & 3) + 8 * (r >> 2) + 4 * lh;
                    part4f[(wc * 64 + row) * M_ + m] = p[mt][r];
                }
        }
    }
    __syncthreads();

    // combine the four col-group partials, coalesced store
    #pragma unroll
    for (int i = 0; i < 2; ++i) {
        const int idx = i * 256 + tid;
        const int row = idx >> 3, m = idx & 7;
        const float v = part4f[(  0 + row) * M_ + m] + part4f[( 64 + row) * M_ + m]
                      + part4f[(128 + row) * M_ + m] + part4f[(192 + row) * M_ + m];
        scores[(long)(row0 + row) * M_ + m] = v;
    }
}

// ---------------------------------------------------------------------------
// Kernel 2: per-graph softmax-normalize -> gate -> exact top-K threshold ->
// binary mask. 1024 threads/block, shfl wave reductions + one cross-wave
// merge (replaces 128 LDS-tree barrier rounds at 256 threads). Same exact
// radix-select semantics (4x8-bit on float bit patterns).
// ---------------------------------------------------------------------------
__global__ __launch_bounds__(1024) void k_mask(
    const float* __restrict__ scores, float* __restrict__ out)
{
    __shared__ float gateLDS[NPG_];          // 16 KB
    __shared__ float wred[16][M_];           // per-wave partials
    __shared__ float gmaxS[M_];
    __shared__ float ginvS[M_];
    __shared__ unsigned hist[256];
    __shared__ unsigned sPrefix;
    __shared__ int sWant;

    const int b    = blockIdx.x;
    const int tid  = threadIdx.x;
    const int wid  = tid >> 6;
    const int lane = tid & 63;
    const float* sb = scores + (long)b * NPG_ * M_;

    // ---- pass A: per-m max ----
    float lv[8];
    #pragma unroll
    for (int m = 0; m < 8; ++m) lv[m] = -INFINITY;
    #pragma unroll
    for (int it = 0; it < 4; ++it) {
        const int n = it * 1024 + tid;
        const float4 s0 = *(const float4*)(sb + (long)n * 8);
        const float4 s1 = *(const float4*)(sb + (long)n * 8 + 4);
        lv[0] = fmaxf(lv[0], s0.x); lv[1] = fmaxf(lv[1], s0.y);
        lv[2] = fmaxf(lv[2], s0.z); lv[3] = fmaxf(lv[3], s0.w);
        lv[4] = fmaxf(lv[4], s1.x); lv[5] = fmaxf(lv[5], s1.y);
        lv[6] = fmaxf(lv[6], s1.z); lv[7] = fmaxf(lv[7], s1.w);
    }
    #pragma unroll
    for (int mask = 1; mask < 64; mask <<= 1)
        #pragma unroll
        for (int m = 0; m < 8; ++m)
            lv[m] = fmaxf(lv[m], __shfl_xor(lv[m], mask, 64));
    if (lane == 0)
        #pragma unroll
        for (int m = 0; m < 8; ++m) wred[wid][m] = lv[m];
    __syncthreads();
    if (tid < 8) {
        float mm = -INFINITY;
        for (int wv = 0; wv < 16; ++wv) mm = fmaxf(mm, wred[wv][tid]);
        gmaxS[tid] = mm;
    }
    __syncthreads();

    float gm[8];
    #pragma unroll
    for (int m = 0; m < 8; ++m) gm[m] = gmaxS[m];    // LDS broadcast

    // ---- pass B: per-m sum of exp(s - max) ----
    float ls[8];
    #pragma unroll
    for (int m = 0; m < 8; ++m) ls[m] = 0.0f;
    #pragma unroll
    for (int it = 0; it < 4; ++it) {
        const int n = it * 1024 + tid;
        const float4 s0 = *(const float4*)(sb + (long)n * 8);
        const float4 s1 = *(const float4*)(sb + (long)n * 8 + 4);
        ls[0] += expf(s0.x - gm[0]); ls[1] += expf(s0.y - gm[1]);
        ls[2] += expf(s0.z - gm[2]); ls[3] += expf(s0.w - gm[3]);
        ls[4] += expf(s1.x - gm[4]); ls[5] += expf(s1.y - gm[5]);
        ls[6] += expf(s1.z - gm[6]); ls[7] += expf(s1.w - gm[7]);
    }
    #pragma unroll
    for (int mask = 1; mask < 64; mask <<= 1)
        #pragma unroll
        for (int m = 0; m < 8; ++m)
            ls[m] += __shfl_xor(ls[m], mask, 64);
    if (lane == 0)
        #pragma unroll
        for (int m = 0; m < 8; ++m) wred[wid][m] = ls[m];
    __syncthreads();
    if (tid < 8) {
        float ss = 0.0f;
        for (int wv = 0; wv < 16; ++wv) ss += wred[wv][tid];
        ginvS[tid] = 1.0f / ss;
    }
    __syncthreads();

    float gi[8];
    #pragma unroll
    for (int m = 0; m < 8; ++m) gi[m] = ginvS[m];

    // ---- pass C: gate[n] = sum_m attn ----
    #pragma unroll
    for (int it = 0; it < 4; ++it) {
        const int n = it * 1024 + tid;
        const float4 s0 = *(const float4*)(sb + (long)n * 8);
        const float4 s1 = *(const float4*)(sb + (long)n * 8 + 4);
        float g = 0.0f;
        g += expf(s0.x - gm[0]) * gi[0];
        g += expf(s0.y - gm[1]) * gi[1];
        g += expf(s0.z - gm[2]) * gi[2];
        g += expf(s0.w - gm[3]) * gi[3];
        g += expf(s1.x - gm[4]) * gi[4];
        g += expf(s1.y - gm[5]) * gi[5];
        g += expf(s1.z - gm[6]) * gi[6];
        g += expf(s1.w - gm[7]) * gi[7];
        gateLDS[n] = g;
    }
    if (tid == 0) { sPrefix = 0u; sWant = KSEL_; }
    __syncthreads();

    // ---- pass D: exact K-th largest via 4x8-bit radix on float bits ----
    #pragma unroll 1
    for (int r = 0; r < 4; ++r) {
        if (tid < 256) hist[tid] = 0u;
        __syncthreads();
        const unsigned pfx = sPrefix;
        const unsigned hm  = (r == 0) ? 0u :
                             (r == 1) ? 0xFF000000u :
                             (r == 2) ? 0xFFFF0000u : 0xFFFFFF00u;
        const int shift = 24 - 8 * r;
        #pragma unroll
        for (int it = 0; it < 4; ++it) {
            const unsigned uv = __float_as_uint(gateLDS[it * 1024 + tid]);
            if ((uv & hm) == pfx)
                atomicAdd(&hist[(uv >> shift) & 255u], 1u);
        }
        __syncthreads();
        if (tid == 0) {
            int want = sWant;
            unsigned acc = 0u;
            for (int bb = 255; bb >= 0; --bb) {
                const unsigned h = hist[bb];
                if (acc + h >= (unsigned)want) {
                    sWant   = want - (int)acc;
                    sPrefix = pfx | ((unsigned)bb << shift);
                    break;
                }
                acc += h;
            }
        }
        __syncthreads();
    }
    const float kth = __uint_as_float(sPrefix);

    // ---- pass E: mask = gate >= kth ----
    #pragma unroll
    for (int it = 0; it < 4; ++it) {
        const int n = it * 1024 + tid;
        out[(long)b * NPG_ + n] = (gateLDS[n] >= kth) ? 1.0f : 0.0f;
    }
}

extern "C" void kernel_launch(void* const* d_in, const int* in_sizes, int n_in,
                              void* d_out, int out_size, void* d_ws, size_t ws_size,
                              hipStream_t stream) {
    const float* x  = (const float*)d_in[0];
    const float* u  = (const float*)d_in[1];
    const float* Wn = (const float*)d_in[2];
    const float* bn = (const float*)d_in[3];
    // d_in[4] = batch (equal segments, implied by layout), d_in[5] = edge_index (unused)

    float* scores = (float*)d_ws;              // N_ * M_ floats = 8 MB

    // WnT hi/lo (512 KB) parked in d_out (1 MB); k_mask fully overwrites out later.
    _Float16* wth = (_Float16*)d_out;
    _Float16* wtl = wth + DQ_ * DN_;
    float* out    = (float*)d_out;

    k_prep <<<DN_, 256, 0, stream>>>(Wn, wth, wtl);
    k_score<<<N_ / 64, 256, 0, stream>>>(x, u, bn, wth, wtl, scores);
    k_mask <<<B_, 1024, 0, stream>>>(scores, out);
}

// Round 5
// 1141.341 us; speedup vs baseline: 1.2217x; 1.2217x over previous
//
#include <hip/hip_runtime.h>
#include <math.h>

#define B_     64
#define NPG_   4096
#define M_     8
#define DN_    512
#define DQ_    256
#define N_     (B_*NPG_)
#define KSEL_  1229          // ceil(0.3 * 4096)

typedef _Float16 f16x8  __attribute__((ext_vector_type(8)));
typedef float    f32x16 __attribute__((ext_vector_type(16)));

// ---------------------------------------------------------------------------
// Kernel 0: split Wn[k][c] (fp32) into transposed fp16 hi/lo halves
// WnT_hi/lo[c][k], k contiguous -> each MFMA B-fragment is one contiguous
// 16B dwordx4 read, L2-resident. Parked in d_out (k_mask overwrites later).
// ---------------------------------------------------------------------------
__global__ __launch_bounds__(256) void k_prep(const float* __restrict__ Wn,
                                              _Float16* __restrict__ th,
                                              _Float16* __restrict__ tl)
{
    const int k = blockIdx.x;      // 0..511
    const int c = threadIdx.x;     // 0..255
    const float w = Wn[k * DQ_ + c];
    const _Float16 h = (_Float16)w;
    th[c * DN_ + k] = h;
    tl[c * DN_ + k] = (_Float16)(w - (float)h);
}

// ---------------------------------------------------------------------------
// Kernel 1: scores[n][m] = sum_c gelu(x[n]·Wn[:,c] + bn[c]) * u[m][b(n)][c]
// fp16x2-split MFMA GEMM (hi*hi + hi*lo + lo*hi, fp32 acc).
// Round-4 postmortem: LDS-staged version was 70% barrier/latency stall +
// 8-way bank-conflicted fragment reads (SQ_LDS_BANK_CONFLICT = 10cy/read).
// Fix: NO LDS staging, NO K-loop barriers. Each lane loads its MFMA
// fragments directly from global: A = 8 consecutive floats of x (32B,
// split to hi/lo f16 in-register), B = contiguous 16B f16x8 from the
// pre-transposed wth/wtl (512KB, L2-resident). 2-deep register ping-pong
// prefetch; waves free-run. Accumulation order identical to the verified
// round-4 kernel.
// ---------------------------------------------------------------------------
__global__ __launch_bounds__(256, 2) void k_score(
    const float* __restrict__ x, const float* __restrict__ u,
    const float* __restrict__ bn,
    const _Float16* __restrict__ wth, const _Float16* __restrict__ wtl,
    float* __restrict__ scores)
{
    __shared__ float usS[M_][DQ_];          // 8 KB
    __shared__ float bnsS[DQ_];             // 1 KB
    __shared__ float part4f[4 * 64 * M_];   // 8 KB
    // total LDS 17 KB

    const int tid = threadIdx.x;
    const int ln  = tid & 63;
    const int wc  = tid >> 6;          // 0..3 : 64-col group
    const int lr  = ln & 31;
    const int lh  = ln >> 5;
    const int row0 = blockIdx.x * 64;
    const int b    = row0 >> 12;       // graph id (64-row blocks never straddle)

    // stage instruction vectors + bias (consumed after the post-loop barrier)
    #pragma unroll
    for (int p = 0; p < 8; ++p) {
        const int idx = p * 256 + tid;
        usS[idx >> 8][idx & 255] = u[((idx >> 8) * B_ + b) * DQ_ + (idx & 255)];
    }
    bnsS[tid] = bn[tid];

    // ---- per-lane fragment base pointers ----
    // A fragment (mt,s) @ kt: x[row0 + mt*32 + lr][kt*32 + s*16 + lh*8 .. +7]
    const float* ap0 = x + (long)(row0 +  0 + lr) * DN_ + lh * 8;
    const float* ap1 = x + (long)(row0 + 32 + lr) * DN_ + lh * 8;
    // B fragment (nt,s) @ kt: wtX[(wc*64 + nt*32 + lr)*512 + kt*32 + s*16 + lh*8 .. +7]
    const long c0 = (long)(wc * 64 +  0 + lr) * DN_ + lh * 8;
    const long c1 = (long)(wc * 64 + 32 + lr) * DN_ + lh * 8;
    const _Float16* bh0 = wth + c0;
    const _Float16* bh1 = wth + c1;
    const _Float16* bl0 = wtl + c0;
    const _Float16* bl1 = wtl + c1;

#define LOADK(XA, BH, BL, KT)                                           \
    {                                                                   \
        const int koff = (KT) * 32;                                     \
        XA[0][0][0] = *(const float4*)(ap0 + koff +  0);                \
        XA[0][0][1] = *(const float4*)(ap0 + koff +  4);                \
        XA[0][1][0] = *(const float4*)(ap0 + koff + 16);                \
        XA[0][1][1] = *(const float4*)(ap0 + koff + 20);                \
        XA[1][0][0] = *(const float4*)(ap1 + koff +  0);                \
        XA[1][0][1] = *(const float4*)(ap1 + koff +  4);                \
        XA[1][1][0] = *(const float4*)(ap1 + koff + 16);                \
        XA[1][1][1] = *(const float4*)(ap1 + koff + 20);                \
        BH[0][0] = *(const f16x8*)(bh0 + koff);                         \
        BH[0][1] = *(const f16x8*)(bh0 + koff + 16);                    \
        BH[1][0] = *(const f16x8*)(bh1 + koff);                         \
        BH[1][1] = *(const f16x8*)(bh1 + koff + 16);                    \
        BL[0][0] = *(const f16x8*)(bl0 + koff);                         \
        BL[0][1] = *(const f16x8*)(bl0 + koff + 16);                    \
        BL[1][0] = *(const f16x8*)(bl1 + koff);                         \
        BL[1][1] = *(const f16x8*)(bl1 + koff + 16);                    \
    }

#define SPLIT8(AH, AL, V0, V1)                                          \
    AH[0] = (_Float16)V0.x; AL[0] = (_Float16)(V0.x - (float)AH[0]);    \
    AH[1] = (_Float16)V0.y; AL[1] = (_Float16)(V0.y - (float)AH[1]);    \
    AH[2] = (_Float16)V0.z; AL[2] = (_Float16)(V0.z - (float)AH[2]);    \
    AH[3] = (_Float16)V0.w; AL[3] = (_Float16)(V0.w - (float)AH[3]);    \
    AH[4] = (_Float16)V1.x; AL[4] = (_Float16)(V1.x - (float)AH[4]);    \
    AH[5] = (_Float16)V1.y; AL[5] = (_Float16)(V1.y - (float)AH[5]);    \
    AH[6] = (_Float16)V1.z; AL[6] = (_Float16)(V1.z - (float)AH[6]);    \
    AH[7] = (_Float16)V1.w; AL[7] = (_Float16)(V1.w - (float)AH[7]);

#define COMPUTE(XA, BH, BL)                                             \
    _Pragma("unroll")                                                   \
    for (int s = 0; s < 2; ++s) {                                       \
        f16x8 ah0, al0, ah1, al1;                                       \
        SPLIT8(ah0, al0, XA[0][s][0], XA[0][s][1]);                     \
        SPLIT8(ah1, al1, XA[1][s][0], XA[1][s][1]);                     \
        _Pragma("unroll")                                               \
        for (int nt = 0; nt < 2; ++nt) {                                \
            acc[0][nt] = __builtin_amdgcn_mfma_f32_32x32x16_f16(        \
                ah0, BH[nt][s], acc[0][nt], 0, 0, 0);                   \
            acc[0][nt] = __builtin_amdgcn_mfma_f32_32x32x16_f16(        \
                ah0, BL[nt][s], acc[0][nt], 0, 0, 0);                   \
            acc[0][nt] = __builtin_amdgcn_mfma_f32_32x32x16_f16(        \
                al0, BH[nt][s], acc[0][nt], 0, 0, 0);                   \
            acc[1][nt] = __builtin_amdgcn_mfma_f32_32x32x16_f16(        \
                ah1, BH[nt][s], acc[1][nt], 0, 0, 0);                   \
            acc[1][nt] = __builtin_amdgcn_mfma_f32_32x32x16_f16(        \
                ah1, BL[nt][s], acc[1][nt], 0, 0, 0);                   \
            acc[1][nt] = __builtin_amdgcn_mfma_f32_32x32x16_f16(        \
                al1, BH[nt][s], acc[1][nt], 0, 0, 0);                   \
        }                                                               \
    }

    f32x16 acc[2][2];
    #pragma unroll
    for (int mt = 0; mt < 2; ++mt)
        #pragma unroll
        for (int nt = 0; nt < 2; ++nt)
            #pragma unroll
            for (int r = 0; r < 16; ++r) acc[mt][nt][r] = 0.0f;

    // 2-deep register ping-pong, no barriers, no LDS in the K-loop
    float4 xaA[2][2][2], xaB[2][2][2];
    f16x8  bhA[2][2], blA[2][2], bhB[2][2], blB[2][2];

    LOADK(xaA, bhA, blA, 0);
    #pragma unroll 1
    for (int kt = 0; kt < 16; kt += 2) {
        LOADK(xaB, bhB, blB, kt + 1);
        COMPUTE(xaA, bhA, blA);
        if (kt + 2 < 16) LOADK(xaA, bhA, blA, kt + 2);
        COMPUTE(xaB, bhB, blB);
    }

    __syncthreads();   // usS/bnsS staging visible to all; part4f not yet touched

    // ---- epilogue: bias + exact gelu, in place (register-only) ----
    #pragma unroll
    for (int mt = 0; mt < 2; ++mt)
        #pragma unroll
        for (int nt = 0; nt < 2; ++nt) {
            const float bnc = bnsS[wc * 64 + nt * 32 + lr];
            #pragma unroll
            for (int r = 0; r < 16; ++r) {
                const float z = acc[mt][nt][r] + bnc;
                acc[mt][nt][r] = 0.5f * z * (1.0f + erff(z * 0.7071067811865476f));
            }
        }

    // dot with 8 instruction vectors; shfl-reduce over the wave's 64 cols
    #pragma unroll 1
    for (int m = 0; m < 8; ++m) {
        const float u0 = usS[m][wc * 64 +  0 + lr];
        const float u1 = usS[m][wc * 64 + 32 + lr];
        float p[2][16];
        #pragma unroll
        for (int mt = 0; mt < 2; ++mt)
            #pragma unroll
            for (int r = 0; r < 16; ++r)
                p[mt][r] = acc[mt][0][r] * u0 + acc[mt][1][r] * u1;
        #pragma unroll
        for (int mask = 1; mask < 32; mask <<= 1)
            #pragma unroll
            for (int mt = 0; mt < 2; ++mt)
                #pragma unroll
                for (int r = 0; r < 16; ++r)
                    p[mt][r] += __shfl_xor(p[mt][r], mask, 64);
        if (lr == m) {                          // lanes m and 32+m: disjoint rows
            #pragma unroll
            for (int mt = 0; mt < 2; ++mt)
                #pragma unroll
                for (int r = 0; r < 16; ++r) {
                    const int row = mt * 32 + (r & 3) + 8 * (r >> 2) + 4 * lh;
                    part4f[(wc * 64 + row) * M_ + m] = p[mt][r];
                }
        }
    }
    __syncthreads();

    // combine the four col-group partials, coalesced store
    #pragma unroll
    for (int i = 0; i < 2; ++i) {
        const int idx = i * 256 + tid;
        const int row = idx >> 3, m = idx & 7;
        const float v = part4f[(  0 + row) * M_ + m] + part4f[( 64 + row) * M_ + m]
                      + part4f[(128 + row) * M_ + m] + part4f[(192 + row) * M_ + m];
        scores[(long)(row0 + row) * M_ + m] = v;
    }
#undef LOADK
#undef SPLIT8
#undef COMPUTE
}

// ---------------------------------------------------------------------------
// Kernel 2: per-graph softmax-normalize -> gate -> exact top-K threshold ->
// binary mask. 1024 threads/block, shfl wave reductions + one cross-wave
// merge. Exact radix-select on float bit patterns. (Verified unchanged.)
// ---------------------------------------------------------------------------
__global__ __launch_bounds__(1024) void k_mask(
    const float* __restrict__ scores, float* __restrict__ out)
{
    __shared__ float gateLDS[NPG_];          // 16 KB
    __shared__ float wred[16][M_];           // per-wave partials
    __shared__ float gmaxS[M_];
    __shared__ float ginvS[M_];
    __shared__ unsigned hist[256];
    __shared__ unsigned sPrefix;
    __shared__ int sWant;

    const int b    = blockIdx.x;
    const int tid  = threadIdx.x;
    const int wid  = tid >> 6;
    const int lane = tid & 63;
    const float* sb = scores + (long)b * NPG_ * M_;

    // ---- pass A: per-m max ----
    float lv[8];
    #pragma unroll
    for (int m = 0; m < 8; ++m) lv[m] = -INFINITY;
    #pragma unroll
    for (int it = 0; it < 4; ++it) {
        const int n = it * 1024 + tid;
        const float4 s0 = *(const float4*)(sb + (long)n * 8);
        const float4 s1 = *(const float4*)(sb + (long)n * 8 + 4);
        lv[0] = fmaxf(lv[0], s0.x); lv[1] = fmaxf(lv[1], s0.y);
        lv[2] = fmaxf(lv[2], s0.z); lv[3] = fmaxf(lv[3], s0.w);
        lv[4] = fmaxf(lv[4], s1.x); lv[5] = fmaxf(lv[5], s1.y);
        lv[6] = fmaxf(lv[6], s1.z); lv[7] = fmaxf(lv[7], s1.w);
    }
    #pragma unroll
    for (int mask = 1; mask < 64; mask <<= 1)
        #pragma unroll
        for (int m = 0; m < 8; ++m)
            lv[m] = fmaxf(lv[m], __shfl_xor(lv[m], mask, 64));
    if (lane == 0)
        #pragma unroll
        for (int m = 0; m < 8; ++m) wred[wid][m] = lv[m];
    __syncthreads();
    if (tid < 8) {
        float mm = -INFINITY;
        for (int wv = 0; wv < 16; ++wv) mm = fmaxf(mm, wred[wv][tid]);
        gmaxS[tid] = mm;
    }
    __syncthreads();

    float gm[8];
    #pragma unroll
    for (int m = 0; m < 8; ++m) gm[m] = gmaxS[m];    // LDS broadcast

    // ---- pass B: per-m sum of exp(s - max) ----
    float ls[8];
    #pragma unroll
    for (int m = 0; m < 8; ++m) ls[m] = 0.0f;
    #pragma unroll
    for (int it = 0; it < 4; ++it) {
        const int n = it * 1024 + tid;
        const float4 s0 = *(const float4*)(sb + (long)n * 8);
        const float4 s1 = *(const float4*)(sb + (long)n * 8 + 4);
        ls[0] += expf(s0.x - gm[0]); ls[1] += expf(s0.y - gm[1]);
        ls[2] += expf(s0.z - gm[2]); ls[3] += expf(s0.w - gm[3]);
        ls[4] += expf(s1.x - gm[4]); ls[5] += expf(s1.y - gm[5]);
        ls[6] += expf(s1.z - gm[6]); ls[7] += expf(s1.w - gm[7]);
    }
    #pragma unroll
    for (int mask = 1; mask < 64; mask <<= 1)
        #pragma unroll
        for (int m = 0; m < 8; ++m)
            ls[m] += __shfl_xor(ls[m], mask, 64);
    if (lane == 0)
        #pragma unroll
        for (int m = 0; m < 8; ++m) wred[wid][m] = ls[m];
    __syncthreads();
    if (tid < 8) {
        float ss = 0.0f;
        for (int wv = 0; wv < 16; ++wv) ss += wred[wv][tid];
        ginvS[tid] = 1.0f / ss;
    }
    __syncthreads();

    float gi[8];
    #pragma unroll
    for (int m = 0; m < 8; ++m) gi[m] = ginvS[m];

    // ---- pass C: gate[n] = sum_m attn ----
    #pragma unroll
    for (int it = 0; it < 4; ++it) {
        const int n = it * 1024 + tid;
        const float4 s0 = *(const float4*)(sb + (long)n * 8);
        const float4 s1 = *(const float4*)(sb + (long)n * 8 + 4);
        float g = 0.0f;
        g += expf(s0.x - gm[0]) * gi[0];
        g += expf(s0.y - gm[1]) * gi[1];
        g += expf(s0.z - gm[2]) * gi[2];
        g += expf(s0.w - gm[3]) * gi[3];
        g += expf(s1.x - gm[4]) * gi[4];
        g += expf(s1.y - gm[5]) * gi[5];
        g += expf(s1.z - gm[6]) * gi[6];
        g += expf(s1.w - gm[7]) * gi[7];
        gateLDS[n] = g;
    }
    if (tid == 0) { sPrefix = 0u; sWant = KSEL_; }
    __syncthreads();

    // ---- pass D: exact K-th largest via 4x8-bit radix on float bits ----
    #pragma unroll 1
    for (int r = 0; r < 4; ++r) {
        if (tid < 256) hist[tid] = 0u;
        __syncthreads();
        const unsigned pfx = sPrefix;
        const unsigned hm  = (r == 0) ? 0u :
                             (r == 1) ? 0xFF000000u :
                             (r == 2) ? 0xFFFF0000u : 0xFFFFFF00u;
        const int shift = 24 - 8 * r;
        #pragma unroll
        for (int it = 0; it < 4; ++it) {
            const unsigned uv = __float_as_uint(gateLDS[it * 1024 + tid]);
            if ((uv & hm) == pfx)
                atomicAdd(&hist[(uv >> shift) & 255u], 1u);
        }
        __syncthreads();
        if (tid == 0) {
            int want = sWant;
            unsigned acc = 0u;
            for (int bb = 255; bb >= 0; --bb) {
                const unsigned h = hist[bb];
                if (acc + h >= (unsigned)want) {
                    sWant   = want - (int)acc;
                    sPrefix = pfx | ((unsigned)bb << shift);
                    break;
                }
                acc += h;
            }
        }
        __syncthreads();
    }
    const float kth = __uint_as_float(sPrefix);

    // ---- pass E: mask = gate >= kth ----
    #pragma unroll
    for (int it = 0; it < 4; ++it) {
        const int n = it * 1024 + tid;
        out[(long)b * NPG_ + n] = (gateLDS[n] >= kth) ? 1.0f : 0.0f;
    }
}

extern "C" void kernel_launch(void* const* d_in, const int* in_sizes, int n_in,
                              void* d_out, int out_size, void* d_ws, size_t ws_size,
                              hipStream_t stream) {
    const float* x  = (const float*)d_in[0];
    const float* u  = (const float*)d_in[1];
    const float* Wn = (const float*)d_in[2];
    const float* bn = (const float*)d_in[3];
    // d_in[4] = batch (equal segments, implied by layout), d_in[5] = edge_index (unused)

    float* scores = (float*)d_ws;              // N_ * M_ floats = 8 MB

    // WnT hi/lo (512 KB) parked in d_out (1 MB); k_mask fully overwrites out later.
    _Float16* wth = (_Float16*)d_out;
    _Float16* wtl = wth + DQ_ * DN_;
    float* out    = (float*)d_out;

    k_prep <<<DN_, 256, 0, stream>>>(Wn, wth, wtl);
    k_score<<<N_ / 64, 256, 0, stream>>>(x, u, bn, wth, wtl, scores);
    k_mask <<<B_, 1024, 0, stream>>>(scores, out);
}